// Round 1
// baseline (2839.746 us; speedup 1.0000x reference)
//
#include <hip/hip_runtime.h>
#include <math.h>

#define C    128
#define C4   32          // C/4 float4 per row
#define GEMM_ROWS 16

// ---------------- degree ----------------
__global__ void ngl_deg_kernel(const int* __restrict__ dst, int E, int* __restrict__ deg) {
    int e = blockIdx.x * blockDim.x + threadIdx.x;
    if (e < E) atomicAdd(&deg[dst[e]], 1);
}

// dis[i] = 1/sqrt(deg_including_selfloop)
__global__ void ngl_dis_kernel(const int* __restrict__ deg, float* __restrict__ dis, int N) {
    int i = blockIdx.x * blockDim.x + threadIdx.x;
    if (i < N) dis[i] = rsqrtf((float)(deg[i] + 1));
}

// agg[i] = x[i] * dis[i]^2   (self-loop term; also zero-initializes agg)
__global__ void ngl_init_agg_kernel(const float4* __restrict__ x4, const float* __restrict__ dis,
                                    float4* __restrict__ agg4, int N) {
    int t = blockIdx.x * blockDim.x + threadIdx.x;
    if (t < N * C4) {
        int i = t >> 5;
        float d = dis[i];
        float w = d * d;
        float4 v = x4[t];
        agg4[t] = make_float4(v.x * w, v.y * w, v.z * w, v.w * w);
    }
}

// per edge: agg[dst] += x[src] * dis[src]*dis[dst]   (32 lanes/edge, float4 each)
__global__ void ngl_scatter_kernel(const int* __restrict__ src, const int* __restrict__ dst, int E,
                                   const float* __restrict__ dis,
                                   const float4* __restrict__ x4,
                                   float* __restrict__ agg) {
    long long t = (long long)blockIdx.x * blockDim.x + threadIdx.x;
    int lane = (int)(t & 31);
    long long e = t >> 5;
    if (e >= E) return;
    int s = src[e];
    int d = dst[e];
    float w = dis[s] * dis[d];
    float4 v = x4[(long long)s * C4 + lane];
    float* o = agg + (long long)d * C + lane * 4;
    atomicAdd(o + 0, v.x * w);
    atomicAdd(o + 1, v.y * w);
    atomicAdd(o + 2, v.z * w);
    atomicAdd(o + 3, v.w * w);
}

__device__ __forceinline__ void fma4(float4& a, float s, const float4& w) {
    a.x += s * w.x; a.y += s * w.y; a.z += s * w.z; a.w += s * w.w;
}

__device__ __forceinline__ float silu1(float v) {
    return v / (1.0f + __expf(-v));
}

// out = silu(agg @ W + b), W staged in LDS (64 KB; gfx950 LDS=160KB/CU)
__global__ __launch_bounds__(256) void ngl_gemm_silu_kernel(
        const float4* __restrict__ agg4, const float4* __restrict__ W4,
        const float4* __restrict__ b4g, float4* __restrict__ out4,
        int N, int tiles_total) {
    __shared__ float4 Wlds[C * C4];          // 64 KB: W[k][c4]
    __shared__ float4 xs[GEMM_ROWS * C4];    // 8 KB
    __shared__ float4 blds[C4];              // 512 B

    int tid = threadIdx.x;
    for (int i = tid; i < C * C4; i += 256) Wlds[i] = W4[i];
    if (tid < C4) blds[tid] = b4g[tid];

    int c4 = tid & 31;    // column group (4 cols)
    int rp = tid >> 5;    // row pair 0..7 -> rows 2rp, 2rp+1

    for (int tile = blockIdx.x; tile < tiles_total; tile += gridDim.x) {
        int row0 = tile * GEMM_ROWS;
        __syncthreads();
        {
            int i0 = tid, i1 = tid + 256;
            long long base = (long long)row0 * C4;
            xs[i0] = (row0 + (i0 >> 5) < N) ? agg4[base + i0] : make_float4(0, 0, 0, 0);
            xs[i1] = (row0 + (i1 >> 5) < N) ? agg4[base + i1] : make_float4(0, 0, 0, 0);
        }
        __syncthreads();

        float4 acc0 = make_float4(0, 0, 0, 0);
        float4 acc1 = make_float4(0, 0, 0, 0);
        const float4* xr0 = &xs[(rp * 2) * C4];
        const float4* xr1 = &xs[(rp * 2 + 1) * C4];
        #pragma unroll 8
        for (int k4 = 0; k4 < C4; ++k4) {
            float4 xa = xr0[k4];
            float4 xb = xr1[k4];
            float4 w0 = Wlds[(k4 * 4 + 0) * C4 + c4];
            float4 w1 = Wlds[(k4 * 4 + 1) * C4 + c4];
            float4 w2 = Wlds[(k4 * 4 + 2) * C4 + c4];
            float4 w3 = Wlds[(k4 * 4 + 3) * C4 + c4];
            fma4(acc0, xa.x, w0); fma4(acc0, xa.y, w1);
            fma4(acc0, xa.z, w2); fma4(acc0, xa.w, w3);
            fma4(acc1, xb.x, w0); fma4(acc1, xb.y, w1);
            fma4(acc1, xb.z, w2); fma4(acc1, xb.w, w3);
        }

        float4 bb = blds[c4];
        int r0 = row0 + rp * 2;
        if (r0 < N) {
            float4 v = acc0;
            v.x = silu1(v.x + bb.x); v.y = silu1(v.y + bb.y);
            v.z = silu1(v.z + bb.z); v.w = silu1(v.w + bb.w);
            out4[(long long)r0 * C4 + c4] = v;
        }
        if (r0 + 1 < N) {
            float4 v = acc1;
            v.x = silu1(v.x + bb.x); v.y = silu1(v.y + bb.y);
            v.z = silu1(v.z + bb.z); v.w = silu1(v.w + bb.w);
            out4[(long long)(r0 + 1) * C4 + c4] = v;
        }
    }
}

extern "C" void kernel_launch(void* const* d_in, const int* in_sizes, int n_in,
                              void* d_out, int out_size, void* d_ws, size_t ws_size,
                              hipStream_t stream) {
    const float* x = (const float*)d_in[0];
    const int*   ei = (const int*)d_in[1];     // int32 per harness convention
    const float* W = (const float*)d_in[2];
    const float* b = (const float*)d_in[3];

    int N = in_sizes[0] / C;
    int E = in_sizes[1] / 2;
    const int* src = ei;
    const int* dst = ei + E;

    char* ws = (char*)d_ws;
    float* agg = (float*)ws;                                   // N*C floats (51.2 MB)
    int*   deg = (int*)(ws + (size_t)N * C * 4);               // N ints
    float* dis = (float*)(ws + (size_t)N * C * 4 + (size_t)N * 4); // N floats

    hipMemsetAsync(deg, 0, (size_t)N * 4, stream);

    ngl_deg_kernel<<<(E + 255) / 256, 256, 0, stream>>>(dst, E, deg);
    ngl_dis_kernel<<<(N + 255) / 256, 256, 0, stream>>>(deg, dis, N);
    ngl_init_agg_kernel<<<(N * C4 + 255) / 256, 256, 0, stream>>>(
        (const float4*)x, dis, (float4*)agg, N);

    long long sthreads = (long long)E * 32;
    int sblocks = (int)((sthreads + 255) / 256);
    ngl_scatter_kernel<<<sblocks, 256, 0, stream>>>(src, dst, E, dis, (const float4*)x, agg);

    int tiles = (N + GEMM_ROWS - 1) / GEMM_ROWS;
    int gblocks = tiles < 2048 ? tiles : 2048;
    ngl_gemm_silu_kernel<<<gblocks, 256, 0, stream>>>(
        (const float4*)agg, (const float4*)W, (const float4*)b, (float4*)d_out, N, tiles);
}

// Round 2
// 511.263 us; speedup vs baseline: 5.5544x; 5.5544x over previous
//
#include <hip/hip_runtime.h>
#include <math.h>

#define C     128
#define C2    64          // float2 per row
#define C4    32          // float4 per row
#define GEMM_ROWS 16
#define SCAN_T 1024

// ---------------- degree ----------------
__global__ void ngl_deg_kernel(const int* __restrict__ dst, int E, int* __restrict__ deg) {
    int e = blockIdx.x * blockDim.x + threadIdx.x;
    if (e < E) atomicAdd(&deg[dst[e]], 1);
}

// dis[i] = 1/sqrt(deg_including_selfloop)
__global__ void ngl_dis_kernel(const int* __restrict__ deg, float* __restrict__ dis, int N) {
    int i = blockIdx.x * blockDim.x + threadIdx.x;
    if (i < N) dis[i] = rsqrtf((float)(deg[i] + 1));
}

// single-block exclusive prefix sum of deg -> offset (N up to ~100k)
__global__ __launch_bounds__(SCAN_T) void ngl_scan_kernel(const int* __restrict__ deg,
                                                          int* __restrict__ offset, int N) {
    __shared__ int sums[SCAN_T];
    int tid = threadIdx.x;
    int per = (N + SCAN_T - 1) / SCAN_T;
    int begin = tid * per;
    int end = begin + per; if (end > N) end = N;
    int s = 0;
    for (int i = begin; i < end; ++i) s += deg[i];
    sums[tid] = s;
    __syncthreads();
    for (int off = 1; off < SCAN_T; off <<= 1) {
        int v = 0;
        if (tid >= off) v = sums[tid - off];
        __syncthreads();
        if (tid >= off) sums[tid] += v;
        __syncthreads();
    }
    int excl = (tid == 0) ? 0 : sums[tid - 1];
    for (int i = begin; i < end; ++i) {
        offset[i] = excl;
        excl += deg[i];
    }
}

// counting-sort scatter: payload[pos] = {src, w}
__global__ void ngl_sort_kernel(const int* __restrict__ src, const int* __restrict__ dst, int E,
                                const float* __restrict__ dis, const int* __restrict__ offset,
                                int* __restrict__ cursor, int2* __restrict__ payload) {
    int e = blockIdx.x * blockDim.x + threadIdx.x;
    if (e >= E) return;
    int s = src[e], d = dst[e];
    int pos = offset[d] + atomicAdd(&cursor[d], 1);
    float w = dis[s] * dis[d];
    payload[pos] = make_int2(s, __float_as_int(w));
}

// one wave per node: registers accumulate the 128-wide row (float2/lane)
__global__ __launch_bounds__(256) void ngl_gather_kernel(
        const float2* __restrict__ x2, const float* __restrict__ dis,
        const int* __restrict__ offset, const int* __restrict__ deg,
        const int2* __restrict__ payload, float2* __restrict__ agg2, int N) {
    int node = blockIdx.x * 4 + (threadIdx.x >> 6);
    int lane = threadIdx.x & 63;
    if (node >= N) return;

    float dn = dis[node];
    float w0 = dn * dn;                       // self-loop norm
    float2 acc = x2[(long long)node * C2 + lane];
    acc.x *= w0; acc.y *= w0;

    int beg = offset[node];
    int cnt = deg[node];

    int2 p = (cnt > 0) ? payload[beg] : make_int2(0, 0);
    for (int i = 0; i < cnt; ++i) {
        int2 cur = p;
        if (i + 1 < cnt) p = payload[beg + i + 1];   // prefetch next payload
        float w = __int_as_float(cur.y);
        float2 v = x2[(long long)cur.x * C2 + lane];
        acc.x += w * v.x;
        acc.y += w * v.y;
    }
    agg2[(long long)node * C2 + lane] = acc;
}

__device__ __forceinline__ void fma4(float4& a, float s, const float4& w) {
    a.x += s * w.x; a.y += s * w.y; a.z += s * w.z; a.w += s * w.w;
}

__device__ __forceinline__ float silu1(float v) {
    return v / (1.0f + __expf(-v));
}

// out = silu(agg @ W + b), W staged in LDS
__global__ __launch_bounds__(256) void ngl_gemm_silu_kernel(
        const float4* __restrict__ agg4, const float4* __restrict__ W4,
        const float4* __restrict__ b4g, float4* __restrict__ out4,
        int N, int tiles_total) {
    __shared__ float4 Wlds[C * C4];          // 64 KB
    __shared__ float4 xs[GEMM_ROWS * C4];    // 8 KB
    __shared__ float4 blds[C4];

    int tid = threadIdx.x;
    for (int i = tid; i < C * C4; i += 256) Wlds[i] = W4[i];
    if (tid < C4) blds[tid] = b4g[tid];

    int c4 = tid & 31;
    int rp = tid >> 5;

    for (int tile = blockIdx.x; tile < tiles_total; tile += gridDim.x) {
        int row0 = tile * GEMM_ROWS;
        __syncthreads();
        {
            int i0 = tid, i1 = tid + 256;
            long long base = (long long)row0 * C4;
            xs[i0] = (row0 + (i0 >> 5) < N) ? agg4[base + i0] : make_float4(0, 0, 0, 0);
            xs[i1] = (row0 + (i1 >> 5) < N) ? agg4[base + i1] : make_float4(0, 0, 0, 0);
        }
        __syncthreads();

        float4 acc0 = make_float4(0, 0, 0, 0);
        float4 acc1 = make_float4(0, 0, 0, 0);
        const float4* xr0 = &xs[(rp * 2) * C4];
        const float4* xr1 = &xs[(rp * 2 + 1) * C4];
        #pragma unroll 8
        for (int k4 = 0; k4 < C4; ++k4) {
            float4 xa = xr0[k4];
            float4 xb = xr1[k4];
            float4 w0 = Wlds[(k4 * 4 + 0) * C4 + c4];
            float4 w1 = Wlds[(k4 * 4 + 1) * C4 + c4];
            float4 w2 = Wlds[(k4 * 4 + 2) * C4 + c4];
            float4 w3 = Wlds[(k4 * 4 + 3) * C4 + c4];
            fma4(acc0, xa.x, w0); fma4(acc0, xa.y, w1);
            fma4(acc0, xa.z, w2); fma4(acc0, xa.w, w3);
            fma4(acc1, xb.x, w0); fma4(acc1, xb.y, w1);
            fma4(acc1, xb.z, w2); fma4(acc1, xb.w, w3);
        }

        float4 bb = blds[c4];
        int r0 = row0 + rp * 2;
        if (r0 < N) {
            float4 v = acc0;
            v.x = silu1(v.x + bb.x); v.y = silu1(v.y + bb.y);
            v.z = silu1(v.z + bb.z); v.w = silu1(v.w + bb.w);
            out4[(long long)r0 * C4 + c4] = v;
        }
        if (r0 + 1 < N) {
            float4 v = acc1;
            v.x = silu1(v.x + bb.x); v.y = silu1(v.y + bb.y);
            v.z = silu1(v.z + bb.z); v.w = silu1(v.w + bb.w);
            out4[(long long)(r0 + 1) * C4 + c4] = v;
        }
    }
}

extern "C" void kernel_launch(void* const* d_in, const int* in_sizes, int n_in,
                              void* d_out, int out_size, void* d_ws, size_t ws_size,
                              hipStream_t stream) {
    const float* x = (const float*)d_in[0];
    const int*   ei = (const int*)d_in[1];
    const float* W = (const float*)d_in[2];
    const float* b = (const float*)d_in[3];

    int N = in_sizes[0] / C;
    int E = in_sizes[1] / 2;
    const int* src = ei;
    const int* dst = ei + E;

    char* ws = (char*)d_ws;
    size_t off = 0;
    float* agg = (float*)(ws + off);      off += (size_t)N * C * 4;   // 51.2 MB
    int2* payload = (int2*)(ws + off);    off += (size_t)E * 8;       // 12.8 MB
    int* deg = (int*)(ws + off);          off += (size_t)N * 4;
    int* offset = (int*)(ws + off);       off += (size_t)N * 4;
    int* cursor = (int*)(ws + off);       off += (size_t)N * 4;
    float* dis = (float*)(ws + off);      off += (size_t)N * 4;

    hipMemsetAsync(deg, 0, (size_t)N * 4, stream);
    hipMemsetAsync(cursor, 0, (size_t)N * 4, stream);

    ngl_deg_kernel<<<(E + 255) / 256, 256, 0, stream>>>(dst, E, deg);
    ngl_dis_kernel<<<(N + 255) / 256, 256, 0, stream>>>(deg, dis, N);
    ngl_scan_kernel<<<1, SCAN_T, 0, stream>>>(deg, offset, N);
    ngl_sort_kernel<<<(E + 255) / 256, 256, 0, stream>>>(src, dst, E, dis, offset, cursor, payload);
    ngl_gather_kernel<<<(N + 3) / 4, 256, 0, stream>>>(
        (const float2*)x, dis, offset, deg, payload, (float2*)agg, N);

    int tiles = (N + GEMM_ROWS - 1) / GEMM_ROWS;
    int gblocks = tiles < 2048 ? tiles : 2048;
    ngl_gemm_silu_kernel<<<gblocks, 256, 0, stream>>>(
        (const float4*)agg, (const float4*)W, (const float4*)b, (float4*)d_out, N, tiles);
}

// Round 3
// 360.114 us; speedup vs baseline: 7.8857x; 1.4197x over previous
//
#include <hip/hip_runtime.h>
#include <math.h>

#define C     128
#define C2    64          // float2 per row
#define C4    32          // float4 per row
#define GEMM_ROWS 16
#define CHUNK 1024        // scan chunk per block (256 threads * 4)

// ---------------- degree ----------------
__global__ void ngl_deg_kernel(const int* __restrict__ dst, int E, int* __restrict__ deg) {
    int e = blockIdx.x * blockDim.x + threadIdx.x;
    if (e < E) atomicAdd(&deg[dst[e]], 1);
}

// scan pass A: per-block sum of deg chunk; fused dis[i] = rsqrt(deg[i]+1)
__global__ __launch_bounds__(256) void ngl_bsum_dis_kernel(
        const int* __restrict__ deg, float* __restrict__ dis,
        int* __restrict__ bsum, int N) {
    __shared__ int red[256];
    int t = threadIdx.x;
    int base = blockIdx.x * CHUNK + t * 4;
    int s = 0;
    #pragma unroll
    for (int j = 0; j < 4; ++j) {
        int i = base + j;
        if (i < N) {
            int dv = deg[i];
            s += dv;
            dis[i] = rsqrtf((float)(dv + 1));
        }
    }
    red[t] = s;
    __syncthreads();
    for (int o = 128; o > 0; o >>= 1) {
        if (t < o) red[t] += red[t + o];
        __syncthreads();
    }
    if (t == 0) bsum[blockIdx.x] = red[0];
}

// scan pass B: single small block, exclusive scan of block sums (NB <= 256)
__global__ __launch_bounds__(256) void ngl_bscan_kernel(int* __restrict__ bsum, int NB) {
    __shared__ int s[256];
    int t = threadIdx.x;
    s[t] = (t < NB) ? bsum[t] : 0;
    __syncthreads();
    for (int o = 1; o < 256; o <<= 1) {
        int v = 0;
        if (t >= o) v = s[t - o];
        __syncthreads();
        if (t >= o) s[t] += v;
        __syncthreads();
    }
    if (t < NB) bsum[t] = (t == 0) ? 0 : s[t - 1];
}

// scan pass C: per-block scan + block offset -> exclusive offset[]
__global__ __launch_bounds__(256) void ngl_offset_kernel(
        const int* __restrict__ deg, const int* __restrict__ boff,
        int* __restrict__ offset, int N) {
    __shared__ int red[256];
    int t = threadIdx.x;
    int base = blockIdx.x * CHUNK + t * 4;
    int v[4];
    int s = 0;
    #pragma unroll
    for (int j = 0; j < 4; ++j) {
        int i = base + j;
        v[j] = (i < N) ? deg[i] : 0;
        s += v[j];
    }
    red[t] = s;
    __syncthreads();
    for (int o = 1; o < 256; o <<= 1) {
        int u = 0;
        if (t >= o) u = red[t - o];
        __syncthreads();
        if (t >= o) red[t] += u;
        __syncthreads();
    }
    int run = boff[blockIdx.x] + ((t == 0) ? 0 : red[t - 1]);
    #pragma unroll
    for (int j = 0; j < 4; ++j) {
        int i = base + j;
        if (i < N) {
            offset[i] = run;
            run += v[j];
        }
    }
}

// counting-sort scatter: payload[pos] = {src, w}
__global__ void ngl_sort_kernel(const int* __restrict__ src, const int* __restrict__ dst, int E,
                                const float* __restrict__ dis, const int* __restrict__ offset,
                                int* __restrict__ cursor, int2* __restrict__ payload) {
    int e = blockIdx.x * blockDim.x + threadIdx.x;
    if (e >= E) return;
    int s = src[e], d = dst[e];
    int pos = offset[d] + atomicAdd(&cursor[d], 1);
    float w = dis[s] * dis[d];
    payload[pos] = make_int2(s, __float_as_int(w));
}

// one wave per node: registers accumulate the 128-wide row (float2/lane)
__global__ __launch_bounds__(256) void ngl_gather_kernel(
        const float2* __restrict__ x2, const float* __restrict__ dis,
        const int* __restrict__ offset, const int* __restrict__ deg,
        const int2* __restrict__ payload, float2* __restrict__ agg2, int N) {
    int node = blockIdx.x * 4 + (threadIdx.x >> 6);
    int lane = threadIdx.x & 63;
    if (node >= N) return;

    float dn = dis[node];
    float w0 = dn * dn;                       // self-loop norm
    float2 acc = x2[(long long)node * C2 + lane];
    acc.x *= w0; acc.y *= w0;

    int beg = offset[node];
    int cnt = deg[node];

    int2 p = (cnt > 0) ? payload[beg] : make_int2(0, 0);
    for (int i = 0; i < cnt; ++i) {
        int2 cur = p;
        if (i + 1 < cnt) p = payload[beg + i + 1];   // prefetch next payload
        float w = __int_as_float(cur.y);
        float2 v = x2[(long long)cur.x * C2 + lane];
        acc.x += w * v.x;
        acc.y += w * v.y;
    }
    agg2[(long long)node * C2 + lane] = acc;
}

__device__ __forceinline__ void fma4(float4& a, float s, const float4& w) {
    a.x += s * w.x; a.y += s * w.y; a.z += s * w.z; a.w += s * w.w;
}

__device__ __forceinline__ float silu1(float v) {
    return v / (1.0f + __expf(-v));
}

// out = silu(agg @ W + b), W staged in LDS
__global__ __launch_bounds__(256) void ngl_gemm_silu_kernel(
        const float4* __restrict__ agg4, const float4* __restrict__ W4,
        const float4* __restrict__ b4g, float4* __restrict__ out4,
        int N, int tiles_total) {
    __shared__ float4 Wlds[C * C4];          // 64 KB
    __shared__ float4 xs[GEMM_ROWS * C4];    // 8 KB
    __shared__ float4 blds[C4];

    int tid = threadIdx.x;
    for (int i = tid; i < C * C4; i += 256) Wlds[i] = W4[i];
    if (tid < C4) blds[tid] = b4g[tid];

    int c4 = tid & 31;
    int rp = tid >> 5;

    for (int tile = blockIdx.x; tile < tiles_total; tile += gridDim.x) {
        int row0 = tile * GEMM_ROWS;
        __syncthreads();
        {
            int i0 = tid, i1 = tid + 256;
            long long base = (long long)row0 * C4;
            xs[i0] = (row0 + (i0 >> 5) < N) ? agg4[base + i0] : make_float4(0, 0, 0, 0);
            xs[i1] = (row0 + (i1 >> 5) < N) ? agg4[base + i1] : make_float4(0, 0, 0, 0);
        }
        __syncthreads();

        float4 acc0 = make_float4(0, 0, 0, 0);
        float4 acc1 = make_float4(0, 0, 0, 0);
        const float4* xr0 = &xs[(rp * 2) * C4];
        const float4* xr1 = &xs[(rp * 2 + 1) * C4];
        #pragma unroll 8
        for (int k4 = 0; k4 < C4; ++k4) {
            float4 xa = xr0[k4];
            float4 xb = xr1[k4];
            float4 w0 = Wlds[(k4 * 4 + 0) * C4 + c4];
            float4 w1 = Wlds[(k4 * 4 + 1) * C4 + c4];
            float4 w2 = Wlds[(k4 * 4 + 2) * C4 + c4];
            float4 w3 = Wlds[(k4 * 4 + 3) * C4 + c4];
            fma4(acc0, xa.x, w0); fma4(acc0, xa.y, w1);
            fma4(acc0, xa.z, w2); fma4(acc0, xa.w, w3);
            fma4(acc1, xb.x, w0); fma4(acc1, xb.y, w1);
            fma4(acc1, xb.z, w2); fma4(acc1, xb.w, w3);
        }

        float4 bb = blds[c4];
        int r0 = row0 + rp * 2;
        if (r0 < N) {
            float4 v = acc0;
            v.x = silu1(v.x + bb.x); v.y = silu1(v.y + bb.y);
            v.z = silu1(v.z + bb.z); v.w = silu1(v.w + bb.w);
            out4[(long long)r0 * C4 + c4] = v;
        }
        if (r0 + 1 < N) {
            float4 v = acc1;
            v.x = silu1(v.x + bb.x); v.y = silu1(v.y + bb.y);
            v.z = silu1(v.z + bb.z); v.w = silu1(v.w + bb.w);
            out4[(long long)(r0 + 1) * C4 + c4] = v;
        }
    }
}

extern "C" void kernel_launch(void* const* d_in, const int* in_sizes, int n_in,
                              void* d_out, int out_size, void* d_ws, size_t ws_size,
                              hipStream_t stream) {
    const float* x = (const float*)d_in[0];
    const int*   ei = (const int*)d_in[1];
    const float* W = (const float*)d_in[2];
    const float* b = (const float*)d_in[3];

    int N = in_sizes[0] / C;
    int E = in_sizes[1] / 2;
    const int* src = ei;
    const int* dst = ei + E;

    char* ws = (char*)d_ws;
    size_t off = 0;
    float* agg = (float*)(ws + off);      off += (size_t)N * C * 4;   // 51.2 MB
    int2* payload = (int2*)(ws + off);    off += (size_t)E * 8;       // 12.8 MB
    int* deg = (int*)(ws + off);          off += (size_t)N * 4;
    int* offset = (int*)(ws + off);       off += (size_t)N * 4;
    int* cursor = (int*)(ws + off);       off += (size_t)N * 4;
    float* dis = (float*)(ws + off);      off += (size_t)N * 4;
    int* bsum = (int*)(ws + off);         off += 1024 * 4;

    int NB = (N + CHUNK - 1) / CHUNK;     // 98 blocks for N=100k (<=256 required)

    hipMemsetAsync(deg, 0, (size_t)N * 4, stream);
    hipMemsetAsync(cursor, 0, (size_t)N * 4, stream);

    ngl_deg_kernel<<<(E + 255) / 256, 256, 0, stream>>>(dst, E, deg);
    ngl_bsum_dis_kernel<<<NB, 256, 0, stream>>>(deg, dis, bsum, N);
    ngl_bscan_kernel<<<1, 256, 0, stream>>>(bsum, NB);
    ngl_offset_kernel<<<NB, 256, 0, stream>>>(deg, bsum, offset, N);
    ngl_sort_kernel<<<(E + 255) / 256, 256, 0, stream>>>(src, dst, E, dis, offset, cursor, payload);
    ngl_gather_kernel<<<(N + 3) / 4, 256, 0, stream>>>(
        (const float2*)x, dis, offset, deg, payload, (float2*)agg, N);

    int tiles = (N + GEMM_ROWS - 1) / GEMM_ROWS;
    int gblocks = tiles < 2048 ? tiles : 2048;
    ngl_gemm_silu_kernel<<<gblocks, 256, 0, stream>>>(
        (const float4*)agg, (const float4*)W, (const float4*)b, (float4*)d_out, N, tiles);
}